// Round 9
// baseline (13.804 us; speedup 1.0000x reference)
//
#include <hip/hip_runtime.h>

// Problem constants (from reference): B=8, N=65536, P=12, G=64
#define BB 8
#define NN 65536
#define PP 12
#define GG 64
#define G3 (GG*GG*GG)
#define NBLOCKS 1024   // (B*N) / (256 threads * 2 points/thread)
#define SLOTS 64       // sharded accumulator/counter slots (16 blocks each)
#define SPAD 16        // 16 dwords = 64B: one cache line per slot

// Module-scope state: zero-initialized at .so load; every call returns it to
// exactly zero (slot-terminal blocks reset counters, finalizer resets
// accumulators) -> deterministic, no cross-call state. Not in d_ws -> never poisoned.
__device__ float    g_acc[SLOTS * SPAD];
__device__ unsigned g_cnt[SLOTS * SPAD];
__device__ unsigned g_l2[SPAD];

// 12-byte packed records: single global_load_dwordx3, no OOB window tricks.
struct __attribute__((packed, aligned(4))) F3 { float x, y, z; };

// Reflect + voxel-index per reference math: normalize plane in f32, reflect,
// idx3 = ceil((r+0.5)*G-0.5), combine in int32 (wraps identically), clip combined.
__device__ __forceinline__ void reflect_idx(
    float px, float py, float pz, float4 pl,
    float& rx, float& ry, float& rz, int& idx)
{
    float nx = pl.x, ny = pl.y, nz = pl.z, d = pl.w;
    float inv = 1.0f / sqrtf(nx * nx + ny * ny + nz * nz);
    nx *= inv; ny *= inv; nz *= inv; d *= inv;

    float t = 2.0f * (px * nx + py * ny + pz * nz + d);
    rx = px - t * nx;
    ry = py - t * ny;
    rz = pz - t * nz;

    int ix = (int)ceilf((rx + 0.5f) * 64.0f - 0.5f);
    int iy = (int)ceilf((ry + 0.5f) * 64.0f - 0.5f);
    int iz = (int)ceilf((rz + 0.5f) * 64.0f - 0.5f);
    idx = ix * 4096 + iy * 64 + iz;
    idx = min(max(idx, 0), G3 - 1);
}

// Generic (slow-path) single-plane contribution, incl. vox predication.
__device__ __forceinline__ float plane_contrib(
    float px, float py, float pz, float4 pl,
    const float* __restrict__ cpb, const float* __restrict__ voxb)
{
    float rx, ry, rz; int idx;
    reflect_idx(px, py, pz, pl, rx, ry, rz, idx);
    float contrib = 0.0f;
    if (voxb[idx] == 0.0f) {
        F3 v = *reinterpret_cast<const F3*>(cpb + (size_t)idx * 3);
        float dx = rx - v.x, dy = ry - v.y, dz = rz - v.z;
        contrib = dx * dx + dy * dy + dz * dz;
    }
    return contrib;
}

__global__ __launch_bounds__(256) void sym_plane_fused_kernel(
    const float* __restrict__ voxel,     // (B, G,G,G)
    const float* __restrict__ points,    // (B, N, 3)
    const float* __restrict__ closest,   // (B, G^3, 3)
    const float* __restrict__ planes,    // (B, P, 4)
    float* __restrict__ out)             // scalar
{
    // XCD-aware mapping: blocks round-robin over the 8 XCDs; batch = blk&7
    // keeps each batch's 4MB of gather tables in ONE XCD's 4MB L2.
    int b  = blockIdx.x & 7;
    int i0 = (blockIdx.x >> 3) * 512 + threadIdx.x;   // point A
    int i1 = i0 + 256;                                // point B (independent chain)

    const float* base = points + (size_t)b * NN * 3;
    F3 p0 = *reinterpret_cast<const F3*>(base + (size_t)i0 * 3);
    F3 p1 = *reinterpret_cast<const F3*>(base + (size_t)i1 * 3);

    const float* cpb  = closest + (size_t)b * G3 * 3;
    const float* voxb = voxel   + (size_t)b * G3;
    const float4* plb = (const float4*)planes + (size_t)b * PP;

    // Plane index for flat positions [12i, 12i+12): q = f>>16.
    int f0a = i0 * 12, f0b = i1 * 12;
    int qa0 = f0a >> 16, qa1 = (f0a + 11) >> 16;
    int qb0 = f0b >> 16, qb1 = (f0b + 11) >> 16;

    float sum;
    if (qa0 == qa1 && qb0 == qb1) {
        // Fast path (all but ~22 threads/batch): one plane per point.
        // Two fully independent chains; both vox gathers issue before either
        // cp gather's branch -> max memory-level parallelism.
        float rx0, ry0, rz0, rx1, ry1, rz1; int idx0, idx1;
        reflect_idx(p0.x, p0.y, p0.z, plb[qa0], rx0, ry0, rz0, idx0);
        reflect_idx(p1.x, p1.y, p1.z, plb[qb0], rx1, ry1, rz1, idx1);

        float vx0 = voxb[idx0];
        float vx1 = voxb[idx1];

        float c0 = 0.0f, c1 = 0.0f;
        if (vx0 == 0.0f) {
            F3 v = *reinterpret_cast<const F3*>(cpb + (size_t)idx0 * 3);
            float dx = rx0 - v.x, dy = ry0 - v.y, dz = rz0 - v.z;
            c0 = dx * dx + dy * dy + dz * dz;
        }
        if (vx1 == 0.0f) {
            F3 v = *reinterpret_cast<const F3*>(cpb + (size_t)idx1 * 3);
            float dx = rx1 - v.x, dy = ry1 - v.y, dz = rz1 - v.z;
            c1 = dx * dx + dy * dy + dz * dz;
        }
        sum = 12.0f * (c0 + c1);
    } else {
        // Slow path: boundary point(s) split weight across two planes.
        float sa, sb;
        if (qa0 == qa1) {
            sa = 12.0f * plane_contrib(p0.x, p0.y, p0.z, plb[qa0], cpb, voxb);
        } else {
            int c = (qa1 << 16) - f0a;
            sa = (float)c        * plane_contrib(p0.x, p0.y, p0.z, plb[qa0], cpb, voxb)
               + (float)(12 - c) * plane_contrib(p0.x, p0.y, p0.z, plb[qa1], cpb, voxb);
        }
        if (qb0 == qb1) {
            sb = 12.0f * plane_contrib(p1.x, p1.y, p1.z, plb[qb0], cpb, voxb);
        } else {
            int c = (qb1 << 16) - f0b;
            sb = (float)c        * plane_contrib(p1.x, p1.y, p1.z, plb[qb0], cpb, voxb)
               + (float)(12 - c) * plane_contrib(p1.x, p1.y, p1.z, plb[qb1], cpb, voxb);
        }
        sum = sa + sb;
    }

    // Block reduction: wave64 shuffle, then LDS across 4 waves.
    for (int off = 32; off > 0; off >>= 1)
        sum += __shfl_down(sum, off, 64);

    __shared__ float wsum[4];
    __shared__ int sfin;
    int lane = threadIdx.x & 63;
    int wid  = threadIdx.x >> 6;
    if (lane == 0) wsum[wid] = sum;
    __syncthreads();

    if (threadIdx.x == 0) {
        float bsum = wsum[0] + wsum[1] + wsum[2] + wsum[3];
        int slot = (int)blockIdx.x & (SLOTS - 1);

        // RELAXED memory-side RMWs only (no release/acquire cache maintenance).
        // Ordering via ack chain: each returning RMW drained with vmcnt(0)
        // before the next issues -> value-add globally complete before count-add.
        float oacc = __hip_atomic_fetch_add(&g_acc[slot * SPAD], bsum,
                                            __ATOMIC_RELAXED, __HIP_MEMORY_SCOPE_AGENT);
        asm volatile("" :: "v"(oacc));
        asm volatile("s_waitcnt vmcnt(0)" ::: "memory");

        sfin = 0;
        unsigned oc = __hip_atomic_fetch_add(&g_cnt[slot * SPAD], 1u,
                                             __ATOMIC_RELAXED, __HIP_MEMORY_SCOPE_AGENT);
        asm volatile("" :: "v"(oc));
        if (oc == (NBLOCKS / SLOTS) - 1) {              // slot-terminal (16th arrival)
            __hip_atomic_store(&g_cnt[slot * SPAD], 0u,
                               __ATOMIC_RELAXED, __HIP_MEMORY_SCOPE_AGENT);
            asm volatile("s_waitcnt vmcnt(0)" ::: "memory");
            unsigned ol = __hip_atomic_fetch_add(&g_l2[0], 1u,
                                                 __ATOMIC_RELAXED, __HIP_MEMORY_SCOPE_AGENT);
            asm volatile("" :: "v"(ol));
            if (ol == SLOTS - 1) {                      // last slot-terminal: finalizer
                __hip_atomic_store(&g_l2[0], 0u,
                                   __ATOMIC_RELAXED, __HIP_MEMORY_SCOPE_AGENT);
                sfin = 1;
            }
        }
    }
    __syncthreads();

    if (sfin) {
        float s = 0.0f;
        if (threadIdx.x < SLOTS) {
            s = __hip_atomic_load(&g_acc[threadIdx.x * SPAD],
                                  __ATOMIC_RELAXED, __HIP_MEMORY_SCOPE_AGENT);
            __hip_atomic_store(&g_acc[threadIdx.x * SPAD], 0.0f,
                               __ATOMIC_RELAXED, __HIP_MEMORY_SCOPE_AGENT);
        }
        if (threadIdx.x < 64) {
            for (int off = 32; off > 0; off >>= 1)
                s += __shfl_down(s, off, 64);
            if (threadIdx.x == 0)
                out[0] = s * (1.0f / (float)(BB * PP));
        }
    }
}

extern "C" void kernel_launch(void* const* d_in, const int* in_sizes, int n_in,
                              void* d_out, int out_size, void* d_ws, size_t ws_size,
                              hipStream_t stream) {
    const float* voxel   = (const float*)d_in[0];
    const float* points  = (const float*)d_in[1];
    const float* closest = (const float*)d_in[2];
    const float* planes  = (const float*)d_in[3];
    float* out = (float*)d_out;

    hipLaunchKernelGGL(sym_plane_fused_kernel, dim3(NBLOCKS), dim3(256), 0, stream,
                       voxel, points, closest, planes, out);
}